// Round 3
// baseline (113.220 us; speedup 1.0000x reference)
//
#include <hip/hip_runtime.h>
#include <hip/hip_bf16.h>
#include <stdint.h>

#define BHn 64
#define Mn 1024
#define SPANn 1024
#define DHn 64
#define NKEY (Mn + SPANn)
#define NITER 17
#define INV32 (1.0f / 32.0f)
// 1/sqrt(512) * log2(e)  -- exp2-direct scaling
#define QSCALE 0.06376580586258808f

typedef short s16x8 __attribute__((ext_vector_type(8)));
typedef float f32x4 __attribute__((ext_vector_type(4)));

#if defined(__has_builtin) && __has_builtin(__builtin_amdgcn_exp2f)
#define EXP2(x) __builtin_amdgcn_exp2f(x)
#else
#define EXP2(x) exp2f(x)
#endif

__device__ __forceinline__ short f2bf(float x) {
    union { float f; unsigned int u; } v; v.f = x;
    unsigned int u = v.u;
    unsigned int r = (u + 0x7FFFu + ((u >> 16) & 1u)) >> 16;
    return (short)r;
}

__device__ __forceinline__ unsigned pack2(float a, float b) {
    __hip_bfloat162 h = __float22bfloat162_rn(float2{a, b});
    union { __hip_bfloat162 h2; unsigned u; } c; c.h2 = h;
    return c.u;
}

__device__ __forceinline__ void gload16(const void* g, void* l) {
    __builtin_amdgcn_global_load_lds(
        (const __attribute__((address_space(1))) void*)g,
        (__attribute__((address_space(3))) void*)l, 16, 0, 0);
}

// Stage a 64x64 bf16 tile into linear LDS; XOR swizzle applied on the SOURCE
// column (read side XORs (row&7)<<4 bytes).
__device__ __forceinline__ void stage64x64(const short* srcbase, int src_stride,
                                           short* ldsbase, int tid) {
    const int scol = (((tid & 7) ^ ((tid >> 3) & 7)) << 3);
    const int wofs = (tid >> 6) << 9;
#pragma unroll
    for (int qh = 0; qh < 2; ++qh) {
        const short* src = srcbase + (size_t)((qh << 5) + (tid >> 3)) * src_stride + scol;
        short* dst = ldsbase + (qh << 11) + wofs;
        gload16(src, dst);
    }
}

// ---------------- fused prepass: K->bf16, V->bf16 transposed, peT ----------------
__global__ void prep_kernel(const float* __restrict__ K, short* __restrict__ Kb,
                            const float* __restrict__ V, short* __restrict__ Vt,
                            const float* __restrict__ pe, short* __restrict__ peT) {
    int blk = blockIdx.x;
    if (blk < 4096) {  // K convert: 4096*256*8 = 8.4M elems
        size_t idx = ((size_t)blk * 256 + threadIdx.x) * 8;
        const float* p = K + idx;
        s16x8 o;
#pragma unroll
        for (int e = 0; e < 8; ++e) o[e] = f2bf(p[e]);
        *(s16x8*)(Kb + idx) = o;
    } else if (blk < 4096 + 2048) {  // V transpose: 64 b * 32 tiles
        __shared__ float tile[64][65];
        int t = blk - 4096;
        int b = t >> 5;
        int n0 = (t & 31) << 6;
        int r = threadIdx.x >> 2;
        int c0 = (threadIdx.x & 3) << 4;
        const float* src = V + ((size_t)b * NKEY + n0 + r) * DHn + c0;
#pragma unroll
        for (int e = 0; e < 16; ++e) tile[r][c0 + e] = src[e];
        __syncthreads();
        short* dst = Vt + ((size_t)b * DHn + r) * NKEY + n0 + c0;
#pragma unroll
        for (int e = 0; e < 16; ++e) dst[e] = f2bf(tile[c0 + e][r]);
    } else {  // peT: 256 blocks
        int idx = (blk - 4096 - 2048) * 256 + threadIdx.x;
        int l = idx >> 6, d = idx & 63;
        peT[l * DHn + d] = f2bf(pe[d * SPANn + l]);
    }
}

// ---------------- main attention kernel ----------------
__global__ __launch_bounds__(256, 2) void attn3_kernel(
    const float* __restrict__ q, const short* __restrict__ Kb,
    const short* __restrict__ Vt, const short* __restrict__ peT,
    const float* __restrict__ cur, float* __restrict__ out) {
    __shared__ short KA[2][4096];   // 16 KB
    __shared__ short VA[2][4096];   // 16 KB
    __shared__ short P[4096];       // 8 KB
    __shared__ float PosF[8192];    // 32 KB: 64 rows x 128-entry f32 ring

    const int b = blockIdx.x & 63;  // g%8==b%8 -> per-b XCD locality
    const int m0 = (blockIdx.x >> 6) << 6;
    const int head = b & 7;
    const int tid = threadIdx.x;
    const int lane = tid & 63;
    const int w = tid >> 6;
    const int l15 = lane & 15;
    const int lh = lane >> 4;

    const float cv = cur[head];
    const float c_h = (cv * (float)SPANn - (float)(SPANn - 1)) * INV32 + 1.0f;

    const short* KbB = Kb + (size_t)b * NKEY * DHn;
    const short* VtB = Vt + (size_t)b * DHn * NKEY;

    // Q fragment (B operand), pre-scaled for exp2-direct
    s16x8 qfrag[2];
    {
        const float* qrow = q + ((size_t)b * Mn + m0 + 16 * w + l15) * DHn;
#pragma unroll
        for (int t2 = 0; t2 < 2; ++t2) {
            int d0 = 32 * t2 + 8 * lh;
#pragma unroll
            for (int e = 0; e < 8; ++e)
                qfrag[t2][e] = f2bf(qrow[d0 + e] * QSCALE);
        }
    }

    f32x4 o_acc[4];
#pragma unroll
    for (int c = 0; c < 4; ++c) o_acc[c] = (f32x4){0.f, 0.f, 0.f, 0.f};
    float zm = 0.f;

    // PE A-fragments held in registers, loaded one chunk ahead (L2-resident)
    const short* peBase = peT + l15 * 64 + 8 * lh;
    s16x8 pe_lo[4], pe_hi[4];
#pragma unroll
    for (int c = 0; c < 4; ++c) {
        pe_lo[c] = *(const s16x8*)(peBase + 16 * c * 64);
        pe_hi[c] = *(const s16x8*)(peBase + 16 * c * 64 + 32);
    }

    // prologue: stage tile 0
    stage64x64(KbB + (size_t)m0 * DHn, DHn, &KA[0][0], tid);
    stage64x64(VtB + m0, NKEY, &VA[0][0], tid);
    __syncthreads();

    const int prow = 16 * w + l15;
    const int swp = (prow & 7) << 4;
    const int rowbase = prow << 7;        // PosF row base (f32 units)
    const int sw2 = (l15 & 7) << 2;       // PosF XOR swizzle (f32-index bits 2-4)

#pragma unroll 1
    for (int t = 0; t < NITER; ++t) {
        const int D = 64 * t;
        const int cb = t & 1;

        // ---- issue next K/V tile staging (drains at bottom barrier) ----
        if (t < NITER - 1) {
            const int n0n = m0 + D + 64;
            stage64x64(KbB + (size_t)n0n * DHn, DHn, &KA[cb ^ 1][0], tid);
            stage64x64(VtB + n0n, NKEY, &VA[cb ^ 1][0], tid);
        }

        // ---- pos GEMM chunk t -> f32 ring (wave-private rows) ----
        if (t < 16) {
#pragma unroll
            for (int c = 0; c < 4; ++c) {
                f32x4 pa = (f32x4){0.f, 0.f, 0.f, 0.f};
                pa = __builtin_amdgcn_mfma_f32_16x16x32_bf16(pe_lo[c], qfrag[0], pa, 0, 0, 0);
                pa = __builtin_amdgcn_mfma_f32_16x16x32_bf16(pe_hi[c], qfrag[1], pa, 0, 0, 0);
                int pidx = ((D + 16 * c + 4 * lh) & 127) ^ sw2;
                *(f32x4*)&PosF[rowbase + pidx] = pa;
            }
        }
        // ---- issue PE loads for chunk t+1 (consumed after next barrier) ----
        if (t < 15) {
            const short* pc = peBase + (size_t)(64 * (t + 1)) * 64;
#pragma unroll
            for (int c = 0; c < 4; ++c) {
                pe_lo[c] = *(const s16x8*)(pc + 16 * c * 64);
                pe_hi[c] = *(const s16x8*)(pc + 16 * c * 64 + 32);
            }
        }

        // ---- S^T = K Q + pos(C-init), exp2, span-mask -> P ----
#pragma unroll
        for (int c = 0; c < 4; ++c) {
            const int lbc = D + 16 * c - 16 * w;  // wave-uniform
            const int lmin = lbc - 15, lmax = lbc + 15;
            char* pdst = (char*)P + prow * 128 + ((32 * c + 8 * lh) ^ swp);
            if ((lmax < 0) || (c_h + (float)lmax * INV32 <= 0.0f)) {
                *(uint2*)pdst = (uint2){0u, 0u};
                continue;
            }
            const int ar = 16 * c + l15;
            const int swk = (ar & 7) << 4;
            const char* kb = (const char*)&KA[cb][0] + ar * 128;
            s16x8 a0 = *(const s16x8*)(kb + ((16 * lh) ^ swk));
            s16x8 a1 = *(const s16x8*)(kb + ((64 + 16 * lh) ^ swk));
            const int lb = lbc + 4 * lh - l15;
            f32x4 ci;
            ci[0] = PosF[rowbase + (((lb + 0) & 127) ^ sw2)];
            ci[1] = PosF[rowbase + (((lb + 1) & 127) ^ sw2)];
            ci[2] = PosF[rowbase + (((lb + 2) & 127) ^ sw2)];
            ci[3] = PosF[rowbase + (((lb + 3) & 127) ^ sw2)];
            f32x4 sa = __builtin_amdgcn_mfma_f32_16x16x32_bf16(a0, qfrag[0], ci, 0, 0, 0);
            sa = __builtin_amdgcn_mfma_f32_16x16x32_bf16(a1, qfrag[1], sa, 0, 0, 0);
            if ((lmin >= 0) && (lmax <= 1023) && (c_h + (float)lmin * INV32 >= 1.0f)) {
                // FAST: mask==1, all l valid
                float p0 = EXP2(sa[0]), p1 = EXP2(sa[1]);
                float p2 = EXP2(sa[2]), p3 = EXP2(sa[3]);
                zm += (p0 + p1) + (p2 + p3);
                *(uint2*)pdst = (uint2){pack2(p0, p1), pack2(p2, p3)};
            } else {
                // SLOW: band edge and/or ramp
                float pm[4];
#pragma unroll
                for (int r = 0; r < 4; ++r) {
                    int l = lb + r;
                    float p = EXP2(sa[r]);
                    p = ((unsigned)l < 1024u) ? p : 0.0f;
                    float mk = fminf(fmaxf((float)l * INV32 + c_h, 0.0f), 1.0f);
                    pm[r] = p * mk;
                    zm += pm[r];
                }
                *(uint2*)pdst = (uint2){pack2(pm[0], pm[1]), pack2(pm[2], pm[3])};
            }
        }

        // ---- PV: O += P * V ----
        {
            const char* pb = (const char*)P + prow * 128;
            s16x8 pf0 = *(const s16x8*)(pb + ((16 * lh) ^ swp));
            s16x8 pf1 = *(const s16x8*)(pb + ((64 + 16 * lh) ^ swp));
            const char* Vbf = (const char*)&VA[cb][0];
            __builtin_amdgcn_s_setprio(1);
#pragma unroll
            for (int c = 0; c < 4; ++c) {
                int vr = 16 * c + l15;
                int swv = (vr & 7) << 4;
                const char* vb = Vbf + vr * 128;
                s16x8 v0 = *(const s16x8*)(vb + ((16 * lh) ^ swv));
                s16x8 v1 = *(const s16x8*)(vb + ((64 + 16 * lh) ^ swv));
                o_acc[c] = __builtin_amdgcn_mfma_f32_16x16x32_bf16(pf0, v0, o_acc[c], 0, 0, 0);
                o_acc[c] = __builtin_amdgcn_mfma_f32_16x16x32_bf16(pf1, v1, o_acc[c], 0, 0, 0);
            }
            __builtin_amdgcn_s_setprio(0);
        }

        __syncthreads();  // drains staging vmcnt; all waves done with cur bufs
    }

    // ---- zm reduction across lh groups (cols already lane-local) ----
    zm += __shfl_xor(zm, 16, 64);
    zm += __shfl_xor(zm, 32, 64);

    // ---- epilogue: out = O / zm ----
#pragma unroll
    for (int r = 0; r < 4; ++r) {
        float zmr = __shfl(zm, 4 * lh + r, 64);
        float dn = 1.0f / (zmr + 1e-20f);
        float* orow = out + ((size_t)b * Mn + m0 + 16 * w + 4 * lh + r) * DHn;
#pragma unroll
        for (int c = 0; c < 4; ++c)
            orow[16 * c + l15] = o_acc[c][r] * dn;
    }
}

extern "C" void kernel_launch(void* const* d_in, const int* in_sizes, int n_in,
                              void* d_out, int out_size, void* d_ws, size_t ws_size,
                              hipStream_t stream) {
    (void)in_sizes; (void)n_in; (void)out_size; (void)ws_size;
    const float* q = (const float*)d_in[0];
    const float* key = (const float*)d_in[1];
    const float* val = (const float*)d_in[2];
    const float* pe = (const float*)d_in[3];
    const float* cur = (const float*)d_in[4];
    float* out = (float*)d_out;

    const size_t KV_ELEMS = (size_t)BHn * NKEY * DHn;  // 8,388,608
    short* Kb = (short*)d_ws;
    short* Vt = Kb + KV_ELEMS;
    short* peT = Vt + KV_ELEMS;

    prep_kernel<<<4096 + 2048 + 256, 256, 0, stream>>>(key, Kb, val, Vt, pe, peT);
    attn3_kernel<<<64 * (Mn / 64), 256, 0, stream>>>(q, Kb, Vt, peT, cur, out);
}

// Round 4
// 97.318 us; speedup vs baseline: 1.1634x; 1.1634x over previous
//
#include <hip/hip_runtime.h>
#include <hip/hip_bf16.h>
#include <stdint.h>

#define BHn 64
#define Mn 1024
#define SPANn 1024
#define DHn 64
#define NKEY (Mn + SPANn)
#define BKn 32
#define NITER 34
#define INV32 (1.0f / 32.0f)
// 1/sqrt(512) * log2(e)  -- exp2-direct scaling
#define QSCALE 0.06376580586258808f

typedef short s16x8 __attribute__((ext_vector_type(8)));
typedef float f32x4 __attribute__((ext_vector_type(4)));

__device__ __forceinline__ short f2bf(float x) {
    union { float f; unsigned int u; } v; v.f = x;
    unsigned int u = v.u;
    unsigned int r = (u + 0x7FFFu + ((u >> 16) & 1u)) >> 16;
    return (short)r;
}
__device__ __forceinline__ float bf2f(short s) {
    union { unsigned int u; float f; } v;
    v.u = ((unsigned int)(unsigned short)s) << 16;
    return v.f;
}
__device__ __forceinline__ unsigned pack2(float a, float b) {
    __hip_bfloat162 h = __float22bfloat162_rn(float2{a, b});
    union { __hip_bfloat162 h2; unsigned u; } c; c.h2 = h;
    return c.u;
}

__device__ __forceinline__ void gload16(const void* g, void* l) {
    __builtin_amdgcn_global_load_lds(
        (const __attribute__((address_space(1))) void*)g,
        (__attribute__((address_space(3))) void*)l, 16, 0, 0);
}

// 32 rows x 64 cols bf16 tile -> linear LDS rows of 128B.
// Source col pre-XOR-swizzled at 16B granule: LDS[r][s] = src[r][s^(r&7)].
__device__ __forceinline__ void stageKP(const short* srcbase, size_t stride,
                                        short* ldsbase, int tid) {
    const int row = tid >> 3;
    const int scol = ((tid & 7) ^ (row & 7)) << 3;  // elems
    const short* src = srcbase + (size_t)row * stride + scol;
    short* dst = ldsbase + ((tid >> 6) << 9);  // wave-uniform; HW adds lane*16B
    gload16(src, dst);
}

// 64 d-rows x 32 n-cols bf16 tile -> LDS rows of 64B, swizzle (row&3) at 16B.
__device__ __forceinline__ void stageV(const short* vtbase, short* ldsbase, int tid) {
    const int row = tid >> 2;
    const int scol = ((tid & 3) ^ (row & 3)) << 3;  // elems
    const short* src = vtbase + (size_t)row * NKEY + scol;
    short* dst = ldsbase + ((tid >> 6) << 9);
    gload16(src, dst);
}

// ---------------- fused prepass: K->bf16, V->bf16 transposed, peT ----------------
__global__ void prep_kernel(const float* __restrict__ K, short* __restrict__ Kb,
                            const float* __restrict__ V, short* __restrict__ Vt,
                            const float* __restrict__ pe, short* __restrict__ peT) {
    int blk = blockIdx.x;
    if (blk < 4096) {
        size_t idx = ((size_t)blk * 256 + threadIdx.x) * 8;
        const float* p = K + idx;
        s16x8 o;
#pragma unroll
        for (int e = 0; e < 8; ++e) o[e] = f2bf(p[e]);
        *(s16x8*)(Kb + idx) = o;
    } else if (blk < 4096 + 2048) {
        __shared__ float tile[64][65];
        int t = blk - 4096;
        int b = t >> 5;
        int n0 = (t & 31) << 6;
        int r = threadIdx.x >> 2;
        int c0 = (threadIdx.x & 3) << 4;
        const float* src = V + ((size_t)b * NKEY + n0 + r) * DHn + c0;
#pragma unroll
        for (int e = 0; e < 16; ++e) tile[r][c0 + e] = src[e];
        __syncthreads();
        short* dst = Vt + ((size_t)b * DHn + r) * NKEY + n0 + c0;
#pragma unroll
        for (int e = 0; e < 16; ++e) dst[e] = f2bf(tile[c0 + e][r]);
    } else {
        int idx = (blk - 4096 - 2048) * 256 + threadIdx.x;
        int l = idx >> 6, d = idx & 63;
        peT[l * DHn + d] = f2bf(pe[d * SPANn + l]);
    }
}

// ---------------- main attention kernel ----------------
__global__ __launch_bounds__(256, 3) void attn4_kernel(
    const float* __restrict__ q, const short* __restrict__ Kb,
    const short* __restrict__ Vt, const short* __restrict__ peT,
    const float* __restrict__ cur, float* __restrict__ out) {
    __shared__ short KA[2][2048];   // 2 x 4 KB  (32 n x 64 d)
    __shared__ short VA[2][2048];   // 2 x 4 KB  (64 d x 32 n)
    __shared__ short PE[2][2048];   // 2 x 4 KB  (32 l x 64 d)
    __shared__ short P[4096];       // 8 KB: 64 q-rows x 128B (32 cols used)
    __shared__ short Ring[8192];    // 16 KB: 64 q-rows x 128-entry bf16 pos ring

    const int b = blockIdx.x & 63;  // g%8==b%8 -> per-b XCD locality
    const int m0 = (blockIdx.x >> 6) << 6;
    const int head = b & 7;
    const int tid = threadIdx.x;
    const int lane = tid & 63;
    const int w = tid >> 6;
    const int l15 = lane & 15;
    const int lh = lane >> 4;

    const float cv = cur[head];
    const float c_h = (cv * (float)SPANn - (float)(SPANn - 1)) * INV32 + 1.0f;

    const short* KbB = Kb + (size_t)b * NKEY * DHn;
    const short* VtB = Vt + (size_t)b * DHn * NKEY;

    // Q fragment (B operand), pre-scaled for exp2-direct
    s16x8 qfrag[2];
    {
        const float* qrow = q + ((size_t)b * Mn + m0 + 16 * w + l15) * DHn;
#pragma unroll
        for (int t2 = 0; t2 < 2; ++t2) {
            int d0 = 32 * t2 + 8 * lh;
#pragma unroll
            for (int e = 0; e < 8; ++e)
                qfrag[t2][e] = f2bf(qrow[d0 + e] * QSCALE);
        }
    }

    f32x4 o_acc[4];
#pragma unroll
    for (int c = 0; c < 4; ++c) o_acc[c] = (f32x4){0.f, 0.f, 0.f, 0.f};
    float zm = 0.f;

    // prologue: stage tile 0
    stageKP(KbB + (size_t)m0 * DHn, DHn, &KA[0][0], tid);
    stageV(VtB + m0, &VA[0][0], tid);
    stageKP(peT, DHn, &PE[0][0], tid);
    __syncthreads();

    const int prow = 16 * w + l15;
    const int swp = (prow & 7) << 4;   // P row XOR (16B granule within 128B row)
    const int ringsw = swp;            // Ring row XOR (same granule, 256B row)
    char* ringrow = (char*)Ring + prow * 256;
    char* prowp = (char*)P + prow * 128;

#pragma unroll 1
    for (int t = 0; t < NITER; ++t) {
        const int D = 32 * t;
        const int cb = t & 1;

        // ---- issue next-tile staging (drains at the bottom barrier) ----
        if (t < NITER - 1) {
            const int n0n = m0 + D + 32;
            stageKP(KbB + (size_t)n0n * DHn, DHn, &KA[cb ^ 1][0], tid);
            stageV(VtB + n0n, &VA[cb ^ 1][0], tid);
            if (t < 31)
                stageKP(peT + (size_t)(D + 32) * DHn, DHn, &PE[cb ^ 1][0], tid);
        }

        // ---- pos GEMM chunk t (l = D..D+31) -> bf16 ring (wave-private rows) ----
        if (t < 32) {
            const char* PEb = (const char*)&PE[cb][0];
#pragma unroll
            for (int c = 0; c < 2; ++c) {
                const int ar = 16 * c + l15;
                const int sw = (ar & 7) << 4;
                const char* base = PEb + ar * 128;
                s16x8 a0 = *(const s16x8*)(base + ((16 * lh) ^ sw));
                s16x8 a1 = *(const s16x8*)(base + ((64 + 16 * lh) ^ sw));
                f32x4 pa = (f32x4){0.f, 0.f, 0.f, 0.f};
                pa = __builtin_amdgcn_mfma_f32_16x16x32_bf16(a0, qfrag[0], pa, 0, 0, 0);
                pa = __builtin_amdgcn_mfma_f32_16x16x32_bf16(a1, qfrag[1], pa, 0, 0, 0);
                const int idx0 = (D + 16 * c + 4 * lh) & 127;
                uint2 pk = {pack2(pa[0], pa[1]), pack2(pa[2], pa[3])};
                *(uint2*)(ringrow + (((idx0 << 1) ^ ringsw))) = pk;
            }
        }

        // ---- S^T = K Q (+ ring pos), exp2, span mask -> P ----
        {
            const char* Kbf = (const char*)&KA[cb][0];
#pragma unroll
            for (int c = 0; c < 2; ++c) {
                const int lbc = D + 16 * c - 16 * w;  // wave-uniform
                const int lmin = lbc - 15, lmax = lbc + 15;
                char* pdst = prowp + ((32 * c + 8 * lh) ^ swp);
                if ((lmax < 0) | (lmin > 1023) |
                    (c_h + (float)lmax * INV32 <= 0.0f)) {
                    *(uint2*)pdst = (uint2){0u, 0u};
                    continue;
                }
                const int ar = 16 * c + l15;
                const int sw = (ar & 7) << 4;
                const char* base = Kbf + ar * 128;
                s16x8 a0 = *(const s16x8*)(base + ((16 * lh) ^ sw));
                s16x8 a1 = *(const s16x8*)(base + ((64 + 16 * lh) ^ sw));
                f32x4 sa = (f32x4){0.f, 0.f, 0.f, 0.f};
                sa = __builtin_amdgcn_mfma_f32_16x16x32_bf16(a0, qfrag[0], sa, 0, 0, 0);
                sa = __builtin_amdgcn_mfma_f32_16x16x32_bf16(a1, qfrag[1], sa, 0, 0, 0);
                const int lb = lbc + 4 * lh - l15;
                float pm[4];
                if ((lmin >= 0) && (lmax <= 1023) &&
                    (c_h + (float)lmin * INV32 >= 1.0f)) {
                    // FAST: mask==1, all l valid
#pragma unroll
                    for (int r = 0; r < 4; ++r) {
                        float pos = bf2f(*(const short*)(
                            ringrow + ((((lb + r) & 127) << 1) ^ ringsw)));
                        pm[r] = __builtin_amdgcn_exp2f(sa[r] + pos);
                        zm += pm[r];
                    }
                } else {
                    // SLOW: band edge and/or ramp
#pragma unroll
                    for (int r = 0; r < 4; ++r) {
                        int l = lb + r;
                        float pos = bf2f(*(const short*)(
                            ringrow + (((l & 127) << 1) ^ ringsw)));
                        float p = __builtin_amdgcn_exp2f(sa[r] + pos);
                        p = ((unsigned)l < 1024u) ? p : 0.0f;
                        float mk = fminf(fmaxf((float)l * INV32 + c_h, 0.0f), 1.0f);
                        pm[r] = p * mk;
                        zm += pm[r];
                    }
                }
                *(uint2*)pdst = (uint2){pack2(pm[0], pm[1]), pack2(pm[2], pm[3])};
            }
        }

        // ---- PV: O += P * V (wave-private P; 1 A-frag, 4 MFMA) ----
        {
            s16x8 pf = *(const s16x8*)(prowp + ((16 * lh) ^ swp));
            const char* Vbf = (const char*)&VA[cb][0];
            __builtin_amdgcn_s_setprio(1);
#pragma unroll
            for (int c = 0; c < 4; ++c) {
                const int vr = 16 * c + l15;
                const int swv = (vr & 3) << 4;
                s16x8 v = *(const s16x8*)(Vbf + vr * 64 + ((16 * lh) ^ swv));
                o_acc[c] = __builtin_amdgcn_mfma_f32_16x16x32_bf16(pf, v, o_acc[c], 0, 0, 0);
            }
            __builtin_amdgcn_s_setprio(0);
        }

        __syncthreads();  // next tiles staged; all waves done with current bufs
    }

    // ---- zm reduction across lh groups (cols already lane-local) ----
    zm += __shfl_xor(zm, 16, 64);
    zm += __shfl_xor(zm, 32, 64);

    // ---- epilogue: out = O / zm ----
#pragma unroll
    for (int r = 0; r < 4; ++r) {
        float zmr = __shfl(zm, 4 * lh + r, 64);
        float dn = 1.0f / (zmr + 1e-20f);
        float* orow = out + ((size_t)b * Mn + m0 + 16 * w + 4 * lh + r) * DHn;
#pragma unroll
        for (int c = 0; c < 4; ++c)
            orow[16 * c + l15] = o_acc[c][r] * dn;
    }
}

extern "C" void kernel_launch(void* const* d_in, const int* in_sizes, int n_in,
                              void* d_out, int out_size, void* d_ws, size_t ws_size,
                              hipStream_t stream) {
    (void)in_sizes; (void)n_in; (void)out_size; (void)ws_size;
    const float* q = (const float*)d_in[0];
    const float* key = (const float*)d_in[1];
    const float* val = (const float*)d_in[2];
    const float* pe = (const float*)d_in[3];
    const float* cur = (const float*)d_in[4];
    float* out = (float*)d_out;

    const size_t KV_ELEMS = (size_t)BHn * NKEY * DHn;  // 8,388,608
    short* Kb = (short*)d_ws;
    short* Vt = Kb + KV_ELEMS;
    short* peT = Vt + KV_ELEMS;

    prep_kernel<<<4096 + 2048 + 256, 256, 0, stream>>>(key, Kb, val, Vt, pe, peT);
    attn4_kernel<<<64 * (Mn / 64), 256, 0, stream>>>(q, Kb, Vt, peT, cur, out);
}